// Round 10
// baseline (192.916 us; speedup 1.0000x reference)
//
#include <hip/hip_runtime.h>
#include <math.h>

#define DIM 64
#define EPSF 1e-15f

#define BW_SHIFT 8
#define BW (1 << BW_SHIFT)       // nodes per bucket (256)
#define CAP_SHIFT 12
#define CAP (1 << CAP_SHIFT)     // bucket capacity 4096 (mean 3061, ~19 sigma)
// NOTE: packing assumes src < 2^17 (N <= 131072) and NB <= 512.

typedef __attribute__((ext_vector_type(8))) short short8;
typedef __attribute__((ext_vector_type(4))) float floatx4;
typedef __attribute__((ext_vector_type(2))) float floatx2;
typedef __attribute__((ext_vector_type(4))) unsigned int uintx4;

// ---------------------------------------------------------------------------
__device__ __forceinline__ float group16_sum(float x) {
#pragma unroll
    for (int off = 1; off <= 8; off <<= 1)
        x += __shfl_xor(x, off, 64);
    return x;
}
__device__ __forceinline__ float group8_sum(float x) {
#pragma unroll
    for (int off = 1; off <= 4; off <<= 1)
        x += __shfl_xor(x, off, 64);
    return x;
}
__device__ __forceinline__ unsigned int f2bf(float x) {
    unsigned int u = __float_as_uint(x);
    u += 0x7fffu + ((u >> 16) & 1u);
    return u >> 16;
}
__device__ __forceinline__ float bflo(unsigned int u) { return __uint_as_float(u << 16); }
__device__ __forceinline__ float bfhi(unsigned int u) { return __uint_as_float(u & 0xFFFF0000u); }

// async global->LDS, 16 B/lane; LDS dest wave-uniform, lane data at +lane*16
__device__ __forceinline__ void dma16(const void* g, void* l) {
    __builtin_amdgcn_global_load_lds(
        (const __attribute__((address_space(1))) unsigned int*)g,
        (__attribute__((address_space(3))) unsigned int*)l, 16, 0, 0);
}
#define WAIT_VM0()   __builtin_amdgcn_s_waitcnt(0x0F70)   /* vmcnt(0), ignore lgkm/exp */
#define WAIT_LGKM0() __builtin_amdgcn_s_waitcnt(0xC07F)   /* lgkmcnt(0), ignore vm/exp */

// ---------------------------------------------------------------------------
// One-time prep: W->bf16, zero-row, bucket cursors to fixed bases b*CAP.
__global__ void prep_kernel(const float* __restrict__ W1, const float* __restrict__ W2,
                            unsigned short* __restrict__ Wbf1, unsigned short* __restrict__ Wbf2,
                            unsigned short* __restrict__ zrowb, int* __restrict__ cursorB, int NB) {
    int i = blockIdx.x * 256 + threadIdx.x;
    if (i < DIM * DIM) {
        Wbf1[i] = (unsigned short)f2bf(W1[i]);
        Wbf2[i] = (unsigned short)f2bf(W2[i]);
    }
    if (i < NB) cursorB[i] = i << CAP_SHIFT;
    if (blockIdx.x == 0 && threadIdx.x < 64) zrowb[threadIdx.x] = 0;
}

// ---------------------------------------------------------------------------
// Stage 1: partition edges into fixed-capacity bucket regions of pairBuf.
__global__ __launch_bounds__(256) void partition_kernel(
    const int* __restrict__ src, const int* __restrict__ dst,
    int* __restrict__ cursorB, unsigned int* __restrict__ pairBuf, int E, int NB)
{
    __shared__ int hist[512], gbase[512], lcur[512];
    int tid = threadIdx.x;
    for (int t = tid; t < NB; t += 256) { hist[t] = 0; lcur[t] = 0; }
    __syncthreads();
    int base = blockIdx.x * 4096;
    unsigned int packed[16]; int bkt[16];
#pragma unroll
    for (int i = 0; i < 16; ++i) {
        int e = base + i * 256 + tid;
        if (e < E) {
            int s = src[e], d = dst[e];
            bkt[i] = d >> BW_SHIFT;
            packed[i] = ((unsigned int)(d & (BW - 1)) << 17) | (unsigned int)s;
            atomicAdd(&hist[bkt[i]], 1);
        } else bkt[i] = -1;
    }
    __syncthreads();
    for (int t = tid; t < NB; t += 256)
        gbase[t] = hist[t] ? atomicAdd(&cursorB[t], hist[t]) : 0;
    __syncthreads();
#pragma unroll
    for (int i = 0; i < 16; ++i) {
        if (bkt[i] >= 0) {
            int rank = atomicAdd(&lcur[bkt[i]], 1);
            int p = gbase[bkt[i]] + rank;
            if (p < ((bkt[i] + 1) << CAP_SHIFT)) pairBuf[p] = packed[i];  // overflow guard
        }
    }
}

// ---------------------------------------------------------------------------
// Merged dispatch: blocks [0, NB) per-bucket counting sort; rest layer-1 GEMM.
union SharedU {
    struct {
        int edges[CAP];
        int stage[CAP];
        int hist[BW], cur[BW], tmp[BW];
    } s;                                  // 35 KB (sort path)
    unsigned int atile[4][16 * 36];       // 9.2 KB (gemm path)
};

__global__ __launch_bounds__(256, 4) void sort_and_gemm_kernel(
    const unsigned int* __restrict__ pairBuf, const int* __restrict__ cursorB,
    int* __restrict__ rowS, int* __restrict__ rowE, int* __restrict__ col,
    const float* __restrict__ in, const unsigned short* __restrict__ Wbf,
    const float* __restrict__ bias, const float* __restrict__ curv,
    unsigned short* __restrict__ outb, int N, int NB)
{
    __shared__ SharedU u;
    if ((int)blockIdx.x < NB) {
        const int b = blockIdx.x, t = threadIdx.x;
        const int base = b << CAP_SHIFT;
        int cnt = cursorB[b] - base;
        if (cnt > CAP) cnt = CAP;
        for (int i = t; i < cnt; i += 256) u.s.edges[i] = (int)pairBuf[base + i];
        u.s.hist[t] = 0;
        __syncthreads();
        for (int i = t; i < cnt; i += 256) atomicAdd(&u.s.hist[u.s.edges[i] >> 17], 1);
        __syncthreads();
        int hv = u.s.hist[t];
        u.s.tmp[t] = hv; __syncthreads();
        for (int off = 1; off < 256; off <<= 1) {
            int x = (t >= off) ? u.s.tmp[t - off] : 0; __syncthreads();
            u.s.tmp[t] += x; __syncthreads();
        }
        int excl = u.s.tmp[t] - hv;
        int node = (b << BW_SHIFT) + t;
        if (node < N) { rowS[node] = base + excl; rowE[node] = base + excl + hv; }
        u.s.cur[t] = excl;
        __syncthreads();
        for (int i = t; i < cnt; i += 256) {
            int v = u.s.edges[i];
            int pos = atomicAdd(&u.s.cur[v >> 17], 1);
            u.s.stage[pos] = v & 0x1FFFF;
        }
        __syncthreads();
        for (int i = t; i < cnt; i += 256) col[base + i] = u.s.stage[i];
    } else {
        const int bid = blockIdx.x - NB;
        const int gemmWaves = (gridDim.x - NB) << 2;
        const float sc = sqrtf(fabsf(curv[0]));
        const float CLIPF = 1.0f - 1e-7f;
        const int lane = threadIdx.x & 63;
        const int wid  = threadIdx.x >> 6;
        const int q = lane >> 4, r = lane & 15;
        const int numBatches = (N + 15) >> 4;
        const float4* in4 = (const float4*)in;

        short8 bfrag[4][2];
#pragma unroll
        for (int nt = 0; nt < 4; ++nt)
#pragma unroll
            for (int ks = 0; ks < 2; ++ks)
                bfrag[nt][ks] = *(const short8*)(Wbf + (nt * 16 + r) * 64 + ks * 32 + q * 8);

        float biasv[4];
#pragma unroll
        for (int nt = 0; nt < 4; ++nt) biasv[nt] = bias[nt * 16 + r];

        for (int batch = (bid << 2) + wid; batch < numBatches; batch += gemmWaves) {
            const int base = batch << 4;
#pragma unroll
            for (int it = 0; it < 4; ++it) {
                int m = it * 4 + q;
                int node = base + m;
                float4 v = make_float4(0.f, 0.f, 0.f, 0.f);
                if (node < N) v = in4[(size_t)node * 16 + r];
                float ss = group16_sum(v.x * v.x + v.y * v.y + v.z * v.z + v.w * v.w);
                float nrm = fmaxf(sqrtf(ss), EPSF);
                float a = fminf(sc * nrm, CLIPF);
                float g = atanhf(a) / (sc * nrm);
                unsigned int lo = f2bf(v.x * g) | (f2bf(v.y * g) << 16);
                unsigned int hi = f2bf(v.z * g) | (f2bf(v.w * g) << 16);
                *(uint2*)&u.atile[wid][m * 36 + r * 2] = make_uint2(lo, hi);
            }
            floatx4 accm[4];
#pragma unroll
            for (int nt = 0; nt < 4; ++nt) accm[nt] = (floatx4){0.f, 0.f, 0.f, 0.f};
#pragma unroll
            for (int ks = 0; ks < 2; ++ks) {
                uintx4 ua = *(const uintx4*)&u.atile[wid][r * 36 + q * 4 + ks * 16];
                short8 af = __builtin_bit_cast(short8, ua);
#pragma unroll
                for (int nt = 0; nt < 4; ++nt)
                    accm[nt] = __builtin_amdgcn_mfma_f32_16x16x32_bf16(af, bfrag[nt][ks], accm[nt], 0, 0, 0);
            }
#pragma unroll
            for (int nt = 0; nt < 4; ++nt)
#pragma unroll
                for (int reg = 0; reg < 4; ++reg) {
                    int node = base + q * 4 + reg;
                    if (node < N)
                        outb[(size_t)node * 64 + nt * 16 + r] =
                            (unsigned short)f2bf(accm[nt][reg] + biasv[nt]);
                }
        }
    }
}

// ---------------------------------------------------------------------------
// DMA-staged bf16 segmented gather. 8-lane group g accumulates 128 B rows of
// its node. Per 8-edge superblock: 8 global_load_lds_dwordx4 (each stages one
// edge-row per group, 8 rows/instr, 64 rows = 8 KB per wave in flight), one
// vmcnt(0), then 8 conflict-free ds_read_b128 per lane + packed adds.
// OOB slots stage the L1-hot zrow. wbuf = this wave's 8 KB LDS region.
__device__ __forceinline__ void gather_rows_dma(
    const char* __restrict__ hb, const int* __restrict__ col,
    int start, int end, int dmax, long long zoff, int g, int r, int lane,
    int colMax, uint4* wbuf, floatx2 acc2[4])
{
    const int roff = r << 4;
    const char* zptr = hb + zoff;
    char* wb = (char*)wbuf;
    for (int sblk = 0; sblk < dmax; sblk += 8) {
        int pos = start + sblk + r;
        int cv = col[min(pos, colMax)];
        int sent = (pos < end) ? cv : -1;
        WAIT_LGKM0();   // prior ds_reads fully retired before DMA overwrites
#pragma unroll
        for (int i = 0; i < 8; ++i) {
            int s = __shfl(sent, (g << 3) + i, 64);
            const char* gp = (s < 0) ? zptr : (hb + ((long long)s << 7));
            dma16(gp + roff, (void*)(wb + i * 1024));
        }
        WAIT_VM0();     // DMA data landed in LDS
#pragma unroll
        for (int i = 0; i < 8; ++i) {
            uint4 uu = *(const uint4*)(wb + i * 1024 + lane * 16);
            acc2[0] += (floatx2){bflo(uu.x), bfhi(uu.x)};
            acc2[1] += (floatx2){bflo(uu.y), bfhi(uu.y)};
            acc2[2] += (floatx2){bflo(uu.z), bfhi(uu.z)};
            acc2[3] += (floatx2){bflo(uu.w), bfhi(uu.w)};
        }
    }
}

// ---------------------------------------------------------------------------
// Layer 2 fused: u = mean gather(h1); h2 = u @ W^T + b -> bf16.
__global__ __launch_bounds__(256, 4) void gather_gemm_mfma(
    const unsigned short* __restrict__ h, const int* __restrict__ rowS,
    const int* __restrict__ rowE, const int* __restrict__ col,
    const unsigned short* __restrict__ Wbf, const float* __restrict__ bias,
    unsigned short* __restrict__ outb, long long zoff, int N, int colMax)
{
    __shared__ unsigned int AtileU[4][16 * 36];
    __shared__ uint4 gbuf[4][512];          // 8 KB DMA staging per wave
    const int lane = threadIdx.x & 63;
    const int wid  = threadIdx.x >> 6;
    const int q = lane >> 4, r = lane & 15;
    const int g8 = lane >> 3, r8 = lane & 7;
    const int wavesTotal = (gridDim.x * blockDim.x) >> 6;
    const int numBatches = (N + 15) >> 4;
    const char* hb = (const char*)h;
    uint4* wbuf = gbuf[wid];

    short8 bfrag[4][2];
#pragma unroll
    for (int nt = 0; nt < 4; ++nt)
#pragma unroll
        for (int ks = 0; ks < 2; ++ks)
            bfrag[nt][ks] = *(const short8*)(Wbf + (nt * 16 + r) * 64 + ks * 32 + q * 8);

    float biasv[4];
#pragma unroll
    for (int nt = 0; nt < 4; ++nt) biasv[nt] = bias[nt * 16 + r];

    for (int batch = (blockIdx.x << 2) + wid; batch < numBatches; batch += wavesTotal) {
        const int base = batch << 4;
#pragma unroll
        for (int it = 0; it < 2; ++it) {
            int m = it * 8 + g8;
            int node = base + m;
            int start = 0, end = 0;
            if (node < N) { start = rowS[node]; end = rowE[node]; }
            int deg = end - start;
            int dmax = max(deg, __shfl_xor(deg, 8, 64));
            dmax = max(dmax, __shfl_xor(dmax, 16, 64));
            dmax = max(dmax, __shfl_xor(dmax, 32, 64));
            floatx2 acc2[4] = {{0.f,0.f},{0.f,0.f},{0.f,0.f},{0.f,0.f}};
            gather_rows_dma(hb, col, start, end, dmax, zoff, g8, r8, lane, colMax, wbuf, acc2);
            float inv = (deg > 0) ? 1.f / (float)deg : 0.f;
            unsigned int u0 = f2bf(acc2[0].x * inv) | (f2bf(acc2[0].y * inv) << 16);
            unsigned int u1 = f2bf(acc2[1].x * inv) | (f2bf(acc2[1].y * inv) << 16);
            unsigned int u2 = f2bf(acc2[2].x * inv) | (f2bf(acc2[2].y * inv) << 16);
            unsigned int u3 = f2bf(acc2[3].x * inv) | (f2bf(acc2[3].y * inv) << 16);
            *(uint4*)&AtileU[wid][m * 36 + r8 * 4] = make_uint4(u0, u1, u2, u3);
        }
        floatx4 accm[4];
#pragma unroll
        for (int nt = 0; nt < 4; ++nt) accm[nt] = (floatx4){0.f, 0.f, 0.f, 0.f};
#pragma unroll
        for (int ks = 0; ks < 2; ++ks) {
            uintx4 ua = *(const uintx4*)&AtileU[wid][r * 36 + q * 4 + ks * 16];
            short8 af = __builtin_bit_cast(short8, ua);
#pragma unroll
            for (int nt = 0; nt < 4; ++nt)
                accm[nt] = __builtin_amdgcn_mfma_f32_16x16x32_bf16(af, bfrag[nt][ks], accm[nt], 0, 0, 0);
        }
#pragma unroll
        for (int nt = 0; nt < 4; ++nt)
#pragma unroll
            for (int reg = 0; reg < 4; ++reg) {
                int node = base + q * 4 + reg;
                if (node < N)
                    outb[(size_t)node * 64 + nt * 16 + r] =
                        (unsigned short)f2bf(accm[nt][reg] + biasv[nt]);
            }
    }
}

// ---------------------------------------------------------------------------
// Final: out = expmap0(mean gather(h2)) -> fp32. 8 nodes per wave, DMA gather.
__global__ __launch_bounds__(256, 4) void gather_expmap8(
    const unsigned short* __restrict__ h, const int* __restrict__ rowS,
    const int* __restrict__ rowE, const int* __restrict__ col,
    const float* __restrict__ curv, float* __restrict__ out,
    long long zoff, int N, int colMax)
{
    __shared__ uint4 gbuf[4][512];          // 8 KB DMA staging per wave
    const float sc = sqrtf(fabsf(curv[0]));
    const int lane = threadIdx.x & 63;
    const int wid  = threadIdx.x >> 6;
    const int g8 = lane >> 3, r8 = lane & 7;
    const int wavesTotal = (gridDim.x * blockDim.x) >> 6;
    const int numBatches = (N + 7) >> 3;
    const char* hb = (const char*)h;
    float4* out4 = (float4*)out;
    uint4* wbuf = gbuf[wid];

    for (int batch = (blockIdx.x << 2) + wid; batch < numBatches; batch += wavesTotal) {
        int node = (batch << 3) + g8;
        int start = 0, end = 0;
        if (node < N) { start = rowS[node]; end = rowE[node]; }
        int deg = end - start;
        int dmax = max(deg, __shfl_xor(deg, 8, 64));
        dmax = max(dmax, __shfl_xor(dmax, 16, 64));
        dmax = max(dmax, __shfl_xor(dmax, 32, 64));
        floatx2 acc2[4] = {{0.f,0.f},{0.f,0.f},{0.f,0.f},{0.f,0.f}};
        gather_rows_dma(hb, col, start, end, dmax, zoff, g8, r8, lane, colMax, wbuf, acc2);
        float inv = (deg > 0) ? 1.f / (float)deg : 0.f;
        float v[8], ss = 0.f;
#pragma unroll
        for (int j = 0; j < 4; ++j) {
            v[2*j]   = acc2[j].x * inv;
            v[2*j+1] = acc2[j].y * inv;
            ss += v[2*j] * v[2*j] + v[2*j+1] * v[2*j+1];
        }
        ss = group8_sum(ss);
        float nrm = fmaxf(sqrtf(ss), EPSF);
        float a = sc * nrm;
        float f = tanhf(a) / a;
        if (node < N) {
            out4[(size_t)node * 16 + r8 * 2]     = make_float4(v[0] * f, v[1] * f, v[2] * f, v[3] * f);
            out4[(size_t)node * 16 + r8 * 2 + 1] = make_float4(v[4] * f, v[5] * f, v[6] * f, v[7] * f);
        }
    }
}

// ---------------------------------------------------------------------------
extern "C" void kernel_launch(void* const* d_in, const int* in_sizes, int n_in,
                              void* d_out, int out_size, void* d_ws, size_t ws_size,
                              hipStream_t stream)
{
    const int*   src  = (const int*)d_in[0];
    const int*   dst  = (const int*)d_in[1];
    const float* emb  = (const float*)d_in[2];
    const float* W1   = (const float*)d_in[3];
    const float* b1   = (const float*)d_in[4];
    const float* W2   = (const float*)d_in[5];
    const float* b2   = (const float*)d_in[6];
    const float* curv = (const float*)d_in[7];
    float*       out  = (float*)d_out;

    const int E = in_sizes[0];
    const int N = in_sizes[2] / DIM;
    const int NB = (N + BW - 1) >> BW_SHIFT;
    const size_t bucketSlots = (size_t)NB << CAP_SHIFT;
    const int colMax = (int)bucketSlots - 1;

    char* ws = (char*)d_ws;
    auto align256 = [](size_t x) { return (x + 255) & ~(size_t)255; };
    size_t off = 0;
    int* cursorB            = (int*)(ws + off);            off += align256(512 * 4);
    int* rowS               = (int*)(ws + off);            off += align256((size_t)N * 4);
    int* rowE               = (int*)(ws + off);            off += align256((size_t)N * 4);
    unsigned int* pairBuf   = (unsigned int*)(ws + off);   off += align256(bucketSlots * 4);
    int* col                = (int*)(ws + off);            off += align256(bucketSlots * 4);
    unsigned short* Wbf1    = (unsigned short*)(ws + off); off += align256((size_t)DIM * DIM * 2);
    unsigned short* Wbf2    = (unsigned short*)(ws + off); off += align256((size_t)DIM * DIM * 2);
    unsigned short* zrowb   = (unsigned short*)(ws + off); off += align256(DIM * 2);
    unsigned short* h1b     = (unsigned short*)(ws + off); off += align256((size_t)N * DIM * 2);
    unsigned short* h2b     = (unsigned short*)(ws + off); off += align256((size_t)N * DIM * 2);

    const long long zoff_h1 = (long long)((char*)zrowb - (char*)h1b);
    const long long zoff_h2 = (long long)((char*)zrowb - (char*)h2b);

    const int chunkBlocks  = (E + 4095) / 4096;
    const int numBatches16 = (N + 15) / 16;
    const int blocks16     = (numBatches16 + 3) / 4;
    const int numBatches8  = (N + 7) / 8;
    const int blocks8      = (numBatches8 + 3) / 4;

    // ---- prep (W->bf16, zrow, bucket cursors) ----
    prep_kernel<<<(DIM * DIM + 255) / 256, 256, 0, stream>>>(W1, W2, Wbf1, Wbf2,
                                                             zrowb, cursorB, NB);
    // ---- CSR partition into fixed buckets ----
    partition_kernel<<<chunkBlocks, 256, 0, stream>>>(src, dst, cursorB, pairBuf, E, NB);
    // ---- merged: per-bucket sort (blocks 0..NB) + layer-1 GEMM (rest) ----
    sort_and_gemm_kernel<<<NB + blocks16, 256, 0, stream>>>(
        pairBuf, cursorB, rowS, rowE, col, emb, Wbf1, b1, curv, h1b, N, NB);
    // ---- layer 2: h2(bf16) = (mean gather h1) @ W2^T + b2 ----
    gather_gemm_mfma<<<blocks16, 256, 0, stream>>>(h1b, rowS, rowE, col, Wbf2, b2, h2b,
                                                   zoff_h1, N, colMax);
    // ---- final: out(fp32) = expmap0(mean gather h2) ----
    gather_expmap8<<<blocks8, 256, 0, stream>>>(h2b, rowS, rowE, col, curv, out,
                                                zoff_h2, N, colMax);
}